// Round 2
// baseline (905.852 us; speedup 1.0000x reference)
//
#include <hip/hip_runtime.h>

typedef __attribute__((ext_vector_type(8))) short s8v;
typedef __attribute__((ext_vector_type(4))) float f4v;

constexpr int BN = 16;
constexpr int TQ = 2048;
constexpr int TK = 2048;
constexpr int DH = 128;
constexpr int KSPLIT = 4;          // av k-dimension split across blocks

__device__ __forceinline__ unsigned short f2bf(float f) {
  unsigned int u = __float_as_uint(f);
  u += 0x7fffu + ((u >> 16) & 1u);   // round-to-nearest-even
  return (unsigned short)(u >> 16);
}
__device__ __forceinline__ float bf2f(unsigned short h) {
  return __uint_as_float(((unsigned int)h) << 16);
}

// ---------------------------------------------------------------------------
// Prep: Q,K fp32 -> split-bf16 hi/lo planes (same [b,t,d] layout, no transpose).
// ---------------------------------------------------------------------------
__global__ __launch_bounds__(256) void prep_kernel(
    const float* __restrict__ Q, const float* __restrict__ K,
    unsigned short* __restrict__ Qhi, unsigned short* __restrict__ Qlo,
    unsigned short* __restrict__ Khi, unsigned short* __restrict__ Klo)
{
  size_t i = ((size_t)blockIdx.x * 256 + threadIdx.x) * 4;
  float4 q = *(const float4*)(Q + i);
  float4 k = *(const float4*)(K + i);
  ushort4 qh, ql, kh, kl;
  qh.x = f2bf(q.x); ql.x = f2bf(q.x - bf2f(qh.x));
  qh.y = f2bf(q.y); ql.y = f2bf(q.y - bf2f(qh.y));
  qh.z = f2bf(q.z); ql.z = f2bf(q.z - bf2f(qh.z));
  qh.w = f2bf(q.w); ql.w = f2bf(q.w - bf2f(qh.w));
  kh.x = f2bf(k.x); kl.x = f2bf(k.x - bf2f(kh.x));
  kh.y = f2bf(k.y); kl.y = f2bf(k.y - bf2f(kh.y));
  kh.z = f2bf(k.z); kl.z = f2bf(k.z - bf2f(kh.z));
  kh.w = f2bf(k.w); kl.w = f2bf(k.w - bf2f(kh.w));
  *(ushort4*)(Qhi + i) = qh; *(ushort4*)(Qlo + i) = ql;
  *(ushort4*)(Khi + i) = kh; *(ushort4*)(Klo + i) = kl;
}

// ---------------------------------------------------------------------------
// Kernel 1: S = Q K^T / sqrt(D) + mask*(-1e4); P = exp(S) -> attn region;
//           Z[b,k] += column sums (softmax over the q axis).
// 128x128 tile/block; split-bf16 3-term MFMA; LDS-staged coalesced epilogue.
// ---------------------------------------------------------------------------
union __align__(16) QKSh {
  struct { unsigned short qhi[128][40], qlo[128][40], khi[128][40], klo[128][40]; } s;
  struct { float t[64][132]; float zr[8][128]; } e;
};

__global__ __launch_bounds__(256) void qk_exp_kernel(
    const unsigned short* __restrict__ Qhi, const unsigned short* __restrict__ Qlo,
    const unsigned short* __restrict__ Khi, const unsigned short* __restrict__ Klo,
    const float* __restrict__ Msk, float* __restrict__ P, float* __restrict__ Z)
{
  __shared__ QKSh sh;

  const int kb = blockIdx.x, qb = blockIdx.y, b = blockIdx.z;
  const int tid = threadIdx.x;
  const int wave = tid >> 6, lane = tid & 63;
  const int wr = wave >> 1, wc = wave & 1;
  const int quad = lane >> 4, l16 = lane & 15;

  f4v acc[4][4];
#pragma unroll
  for (int i = 0; i < 4; ++i)
#pragma unroll
    for (int j = 0; j < 4; ++j)
      acc[i][j] = (f4v){0.f, 0.f, 0.f, 0.f};

  const unsigned short* Qbh = Qhi + ((size_t)b * TQ + (size_t)qb * 128) * DH;
  const unsigned short* Qbl = Qlo + ((size_t)b * TQ + (size_t)qb * 128) * DH;
  const unsigned short* Kbh = Khi + ((size_t)b * TK + (size_t)kb * 128) * DH;
  const unsigned short* Kbl = Klo + ((size_t)b * TK + (size_t)kb * 128) * DH;

  for (int dc = 0; dc < DH; dc += 32) {
    __syncthreads();
#pragma unroll
    for (int it = 0; it < 2; ++it) {
      int idx = it * 256 + tid;
      int r = idx >> 2, c = (idx & 3) * 8;
      size_t go = (size_t)r * DH + dc + c;
      *(uint4*)&sh.s.qhi[r][c] = *(const uint4*)(Qbh + go);
      *(uint4*)&sh.s.qlo[r][c] = *(const uint4*)(Qbl + go);
      *(uint4*)&sh.s.khi[r][c] = *(const uint4*)(Kbh + go);
      *(uint4*)&sh.s.klo[r][c] = *(const uint4*)(Kbl + go);
    }
    __syncthreads();

    s8v ah[4], al[4], bh[4], bl[4];
#pragma unroll
    for (int i = 0; i < 4; ++i) {
      ah[i] = *(const s8v*)&sh.s.qhi[wr*64 + i*16 + l16][quad*8];
      al[i] = *(const s8v*)&sh.s.qlo[wr*64 + i*16 + l16][quad*8];
      bh[i] = *(const s8v*)&sh.s.khi[wc*64 + i*16 + l16][quad*8];
      bl[i] = *(const s8v*)&sh.s.klo[wc*64 + i*16 + l16][quad*8];
    }
#pragma unroll
    for (int i = 0; i < 4; ++i)
#pragma unroll
      for (int j = 0; j < 4; ++j) {
        acc[i][j] = __builtin_amdgcn_mfma_f32_16x16x32_bf16(ah[i], bh[j], acc[i][j], 0, 0, 0);
        acc[i][j] = __builtin_amdgcn_mfma_f32_16x16x32_bf16(al[i], bh[j], acc[i][j], 0, 0, 0);
        acc[i][j] = __builtin_amdgcn_mfma_f32_16x16x32_bf16(ah[i], bl[j], acc[i][j], 0, 0, 0);
      }
  }

  // Epilogue: acc tile rows = wr*64+i*16+quad*4+r, cols = wc*64+j*16+l16.
  // Two passes of 64 rows through LDS -> row-major coalesced mask/exp/store.
  const float scale = 0.08838834764831845f;  // 1/sqrt(128)
  const int cb = (tid & 31) * 4;   // fixed 4-col group per thread
  const int rg = tid >> 5;         // row-group 0..7
  f4v zpart = (f4v){0.f, 0.f, 0.f, 0.f};

#pragma unroll
  for (int p = 0; p < 2; ++p) {
    __syncthreads();
    if (wr == p) {
#pragma unroll
      for (int i = 0; i < 4; ++i)
#pragma unroll
        for (int j = 0; j < 4; ++j)
#pragma unroll
          for (int r = 0; r < 4; ++r)
            sh.e.t[i*16 + quad*4 + r][wc*64 + j*16 + l16] = acc[i][j][r] * scale;
    }
    __syncthreads();
    size_t rowbase = (size_t)b * TQ + qb * 128 + p * 64;
#pragma unroll
    for (int it = 0; it < 8; ++it) {
      int r = it * 8 + rg;
      float4 sv = *(const float4*)&sh.e.t[r][cb];
      size_t off = (rowbase + r) * TK + kb * 128 + cb;
      float4 mv = *(const float4*)(Msk + off);
      float4 pv;
      pv.x = __expf(sv.x - 10000.0f * mv.x);
      pv.y = __expf(sv.y - 10000.0f * mv.y);
      pv.z = __expf(sv.z - 10000.0f * mv.z);
      pv.w = __expf(sv.w - 10000.0f * mv.w);
      *(float4*)(P + off) = pv;
      zpart[0] += pv.x; zpart[1] += pv.y; zpart[2] += pv.z; zpart[3] += pv.w;
    }
  }

  // Z column-sum reduce: 8 row-groups share each col group -> LDS -> 128 atomics.
  __syncthreads();
  *(float4*)&sh.e.zr[rg][cb] = (float4){zpart[0], zpart[1], zpart[2], zpart[3]};
  __syncthreads();
  if (tid < 128) {
    float s = 0.f;
#pragma unroll
    for (int k = 0; k < 8; ++k) s += sh.e.zr[k][tid];
    atomicAdd(&Z[b * TK + kb * 128 + tid], s);
  }
}

// ---------------------------------------------------------------------------
// Kernel 2a: V[b,k,d] -> Vt_hi/Vt_lo[b,d,k] (bf16 split planes) via LDS tile.
// ---------------------------------------------------------------------------
__global__ __launch_bounds__(256) void vtrans_kernel(
    const float* __restrict__ V, unsigned short* __restrict__ Vthi,
    unsigned short* __restrict__ Vtlo)
{
  __shared__ float tile[64][65];
  const int k0 = blockIdx.x * 64, d0 = blockIdx.y * 64, b = blockIdx.z;
  const int tid = threadIdx.x;
#pragma unroll
  for (int i = 0; i < 4; ++i) {
    int idx = i * 256 + tid;
    int r = idx >> 4, c = (idx & 15) * 4;
    float4 v = *(const float4*)(V + ((size_t)b * TK + k0 + r) * DH + d0 + c);
    tile[r][c] = v.x; tile[r][c+1] = v.y; tile[r][c+2] = v.z; tile[r][c+3] = v.w;
  }
  __syncthreads();
  const int dr = tid >> 2, kq = (tid & 3) * 16;
  size_t base = ((size_t)b * DH + d0 + dr) * TK + k0 + kq;
  unsigned short hbuf[16], lbuf[16];
#pragma unroll
  for (int j = 0; j < 16; ++j) {
    float f = tile[kq + j][dr];
    unsigned short h = f2bf(f);
    hbuf[j] = h;
    lbuf[j] = f2bf(f - bf2f(h));
  }
#pragma unroll
  for (int m = 0; m < 4; ++m) {
    ushort4 hv = make_ushort4(hbuf[4*m], hbuf[4*m+1], hbuf[4*m+2], hbuf[4*m+3]);
    ushort4 lv = make_ushort4(lbuf[4*m], lbuf[4*m+1], lbuf[4*m+2], lbuf[4*m+3]);
    *(ushort4*)(Vthi + base + 4*m) = hv;
    *(ushort4*)(Vtlo + base + 4*m) = lv;
  }
}

// Kernel 2b: Rz = 1/Z
__global__ __launch_bounds__(256) void rz_kernel(const float* __restrict__ Z,
                                                 float* __restrict__ Rz) {
  int i = blockIdx.x * 256 + threadIdx.x;
  Rz[i] = 1.0f / Z[i];
}

// ---------------------------------------------------------------------------
// Kernel 3: attn = P * Rz[k] (in place), ctx += attn @ V (k-split, atomics).
// ctx^T = V^T @ attn^T so both MFMA operands are k-contiguous.
// ---------------------------------------------------------------------------
union __align__(16) SH3 {
  struct {
    unsigned short ahi[128][40];
    unsigned short alo[128][40];
    unsigned short vhi[128][40];
    unsigned short vlo[128][40];
  } s;
  float ctx[64][130];
};

__global__ __launch_bounds__(256) void av_kernel(
    float* __restrict__ Attn, const unsigned short* __restrict__ Vthi,
    const unsigned short* __restrict__ Vtlo, const float* __restrict__ Rz,
    float* __restrict__ Ctx)
{
  __shared__ SH3 sh;
  const int qb = blockIdx.x, ks = blockIdx.y, b = blockIdx.z;
  const int tid = threadIdx.x;
  const int wave = tid >> 6, lane = tid & 63;
  const int wr = wave >> 1, wc = wave & 1;
  const int quad = lane >> 4, l16 = lane & 15;

  f4v acc[4][4];
#pragma unroll
  for (int i = 0; i < 4; ++i)
#pragma unroll
    for (int j = 0; j < 4; ++j)
      acc[i][j] = (f4v){0.f, 0.f, 0.f, 0.f};

  float* attnB = Attn + ((size_t)b * TQ + (size_t)qb * 128) * TK;
  const unsigned short* vhB = Vthi + (size_t)b * DH * TK;
  const unsigned short* vlB = Vtlo + (size_t)b * DH * TK;
  const float* rzB = Rz + (size_t)b * TK;

  const int kc0 = ks * (TK / KSPLIT);
  const int kc1 = kc0 + (TK / KSPLIT);
  for (int kc = kc0; kc < kc1; kc += 32) {
    __syncthreads();
#pragma unroll
    for (int i = 0; i < 4; ++i) {
      int idx = i * 256 + tid;
      int r = idx >> 3, c = (idx & 7) * 4;
      size_t off = (size_t)r * TK + kc + c;
      float4 pv = *(const float4*)(attnB + off);
      float4 rv = *(const float4*)(rzB + kc + c);
      float4 av;
      av.x = pv.x * rv.x; av.y = pv.y * rv.y;
      av.z = pv.z * rv.z; av.w = pv.w * rv.w;
      *(float4*)(attnB + off) = av;  // final normalized attn output
      unsigned short h;
      h = f2bf(av.x); sh.s.ahi[r][c+0] = h; sh.s.alo[r][c+0] = f2bf(av.x - bf2f(h));
      h = f2bf(av.y); sh.s.ahi[r][c+1] = h; sh.s.alo[r][c+1] = f2bf(av.y - bf2f(h));
      h = f2bf(av.z); sh.s.ahi[r][c+2] = h; sh.s.alo[r][c+2] = f2bf(av.z - bf2f(h));
      h = f2bf(av.w); sh.s.ahi[r][c+3] = h; sh.s.alo[r][c+3] = f2bf(av.w - bf2f(h));
    }
#pragma unroll
    for (int i = 0; i < 2; ++i) {
      int idx = i * 256 + tid;
      int d = idx >> 2, part = (idx & 3) * 8;
      *(uint4*)&sh.s.vhi[d][part] = *(const uint4*)(vhB + (size_t)d * TK + kc + part);
      *(uint4*)&sh.s.vlo[d][part] = *(const uint4*)(vlB + (size_t)d * TK + kc + part);
    }
    __syncthreads();

    s8v vh[4], vl[4], ah[4], al[4];
#pragma unroll
    for (int i = 0; i < 4; ++i) {
      vh[i] = *(const s8v*)&sh.s.vhi[wr*64 + i*16 + l16][quad*8];
      vl[i] = *(const s8v*)&sh.s.vlo[wr*64 + i*16 + l16][quad*8];
      ah[i] = *(const s8v*)&sh.s.ahi[wc*64 + i*16 + l16][quad*8];
      al[i] = *(const s8v*)&sh.s.alo[wc*64 + i*16 + l16][quad*8];
    }
#pragma unroll
    for (int i = 0; i < 4; ++i)
#pragma unroll
      for (int j = 0; j < 4; ++j) {
        acc[i][j] = __builtin_amdgcn_mfma_f32_16x16x32_bf16(vh[i], ah[j], acc[i][j], 0, 0, 0);
        acc[i][j] = __builtin_amdgcn_mfma_f32_16x16x32_bf16(vl[i], ah[j], acc[i][j], 0, 0, 0);
        acc[i][j] = __builtin_amdgcn_mfma_f32_16x16x32_bf16(vh[i], al[j], acc[i][j], 0, 0, 0);
      }
  }

  // Epilogue: acc holds ctx^T tiles (m=d, n=q). Transpose via LDS, atomic-add
  // partials into Ctx (zero-initialized by kernel_launch's memset).
#pragma unroll
  for (int p = 0; p < 2; ++p) {
    __syncthreads();
    if (wc == p) {
#pragma unroll
      for (int i = 0; i < 4; ++i)
#pragma unroll
        for (int j = 0; j < 4; ++j)
#pragma unroll
          for (int r = 0; r < 4; ++r)
            sh.ctx[j*16 + l16][wr*64 + i*16 + quad*4 + r] = acc[i][j][r];
    }
    __syncthreads();
#pragma unroll
    for (int i = 0; i < 8; ++i) {
      int idx = i * 256 + tid;
      int r = idx >> 5, c = (idx & 31) * 4;
      float* dst = Ctx + ((size_t)b * TQ + qb * 128 + p * 64 + r) * DH + c;
      atomicAdd(dst + 0, sh.ctx[r][c]);
      atomicAdd(dst + 1, sh.ctx[r][c+1]);
      atomicAdd(dst + 2, sh.ctx[r][c+2]);
      atomicAdd(dst + 3, sh.ctx[r][c+3]);
    }
  }
}

// ---------------------------------------------------------------------------
extern "C" void kernel_launch(void* const* d_in, const int* in_sizes, int n_in,
                              void* d_out, int out_size, void* d_ws, size_t ws_size,
                              hipStream_t stream)
{
  const float* Q = (const float*)d_in[0];
  const float* K = (const float*)d_in[1];
  const float* V = (const float*)d_in[2];
  const float* M = (const float*)d_in[3];

  float* ctx  = (float*)d_out;
  float* attn = ctx + (size_t)BN * TQ * DH;   // outputs: context ++ attn

  // ws layout: Z(128K) | Rz(128K) | @1MB: Vthi(8M) Vtlo(8M) Qhi(8M) Qlo(8M) Khi(8M) Klo(8M)
  char* ws = (char*)d_ws;
  float* Z  = (float*)ws;
  float* Rz = (float*)(ws + (128 << 10));
  const size_t PLANE = (size_t)BN * DH * TK;  // 4M elems, 8 MB as ushort
  unsigned short* Vthi = (unsigned short*)(ws + (1 << 20));
  unsigned short* Vtlo = Vthi + PLANE;
  unsigned short* Qhi  = Vtlo + PLANE;
  unsigned short* Qlo  = Qhi + PLANE;
  unsigned short* Khi  = Qlo + PLANE;
  unsigned short* Klo  = Khi + PLANE;

  hipMemsetAsync(Z, 0, (size_t)BN * TK * sizeof(float), stream);
  hipMemsetAsync(ctx, 0, (size_t)BN * TQ * DH * sizeof(float), stream);
  prep_kernel<<<dim3((BN*TQ*DH/4)/256), 256, 0, stream>>>(Q, K, Qhi, Qlo, Khi, Klo);
  vtrans_kernel<<<dim3(TK/64, DH/64, BN), 256, 0, stream>>>(V, Vthi, Vtlo);
  qk_exp_kernel<<<dim3(TK/128, TQ/128, BN), 256, 0, stream>>>(Qhi, Qlo, Khi, Klo, M, attn, Z);
  rz_kernel<<<dim3((BN*TK)/256), 256, 0, stream>>>(Z, Rz);
  av_kernel<<<dim3(TQ/128, KSPLIT, BN), 256, 0, stream>>>(attn, Vthi, Vtlo, Rz, ctx);
}